// Round 2
// baseline (245.508 us; speedup 1.0000x reference)
//
#include <hip/hip_runtime.h>

#define N_TOK   524288
#define KC      256
#define D       32
#define EPSF    1e-6f
#define TPT     64                 // tokens per tile
#define NTILES  (N_TOK / TPT)      // 8192
#define NBLK    768
#define BLKT    256

// ---------------- main kernel: argmin + rotation + per-block histogram ----------------
__global__ __launch_bounds__(BLKT) void vq_main(
    const float* __restrict__ x, const float* __restrict__ cb,
    float* __restrict__ out_rot, float* __restrict__ out_idx,
    float* __restrict__ ws_hist, float* __restrict__ out_cnt, int use_ws)
{
    __shared__ float ct[D][KC];    // codebook transposed: ct[k][code]  (32 KB)
    __shared__ float c2s[KC];      // ||c||^2 per code, numpy pairwise order
    __shared__ float xt[D][TPT];   // x tile transposed: xt[k][tok]     (8 KB)
    __shared__ float x2s[TPT];     // ||x||^2 per token, numpy pairwise order
    __shared__ int   bidx[TPT];    // winning code per token in tile
    __shared__ float hist[KC];     // per-block histogram

    const int tid = threadIdx.x;

    // ---- stage codebook transposed + c2 (numpy pairwise), zero hist ----
    {
#pragma clang fp contract(off)
        const float4* cb4 = (const float4*)(cb + (size_t)tid * D);
        float4 r[8];
#pragma unroll
        for (int j = 0; j < 8; j++) r[j] = cb4[j];
        float t[32];
#pragma unroll
        for (int j = 0; j < 8; j++) {
            t[4 * j + 0] = r[j].x * r[j].x;
            t[4 * j + 1] = r[j].y * r[j].y;
            t[4 * j + 2] = r[j].z * r[j].z;
            t[4 * j + 3] = r[j].w * r[j].w;
        }
        // numpy pairwise_sum, n=32, scalar unroll-8 path
        float pr[8];
#pragma unroll
        for (int j = 0; j < 8; j++)
            pr[j] = ((t[j] + t[j + 8]) + t[j + 16]) + t[j + 24];
        c2s[tid] = ((pr[0] + pr[1]) + (pr[2] + pr[3])) + ((pr[4] + pr[5]) + (pr[6] + pr[7]));
#pragma unroll
        for (int j = 0; j < 8; j++) {
            ct[4 * j + 0][tid] = r[j].x;
            ct[4 * j + 1][tid] = r[j].y;
            ct[4 * j + 2][tid] = r[j].z;
            ct[4 * j + 3][tid] = r[j].w;
        }
        hist[tid] = 0.f;
    }
    const int tt = tid >> 4;   // token group 0..15 (4 tokens each)
    const int tc = tid & 15;   // code group 0..15  (8 codes per chunk)
    __syncthreads();

    for (int tile = blockIdx.x; tile < NTILES; tile += gridDim.x) {
        const int tok0 = tile * TPT;

        // ---- stage x tile transposed (coalesced read, scalar transpose writes) ----
        {
            const float4* xg = (const float4*)(x + (size_t)tok0 * D + (size_t)tid * 8);
            float4 a = xg[0], b = xg[1];
            int tok = tid >> 2;
            int k0  = (tid & 3) * 8;
            xt[k0 + 0][tok] = a.x; xt[k0 + 1][tok] = a.y;
            xt[k0 + 2][tok] = a.z; xt[k0 + 3][tok] = a.w;
            xt[k0 + 4][tok] = b.x; xt[k0 + 5][tok] = b.y;
            xt[k0 + 6][tok] = b.z; xt[k0 + 7][tok] = b.w;
        }
        __syncthreads();

        // ---- x2 per token, numpy pairwise order (threads 0..63) ----
        if (tid < TPT) {
#pragma clang fp contract(off)
            float t[32];
#pragma unroll
            for (int k = 0; k < 32; k++) { float v = xt[k][tid]; t[k] = v * v; }
            float pr[8];
#pragma unroll
            for (int j = 0; j < 8; j++)
                pr[j] = ((t[j] + t[j + 8]) + t[j + 16]) + t[j + 24];
            x2s[tid] = ((pr[0] + pr[1]) + (pr[2] + pr[3])) + ((pr[4] + pr[5]) + (pr[6] + pr[7]));
        }
        __syncthreads();

        // ---- scores + argmin: thread tile = 4 tokens x 8 codes, 2 chunks of 128 codes ----
        float x4[4];
#pragma unroll
        for (int i = 0; i < 4; i++) x4[i] = x2s[tt * 4 + i];

        float bestv[4] = {3.4e38f, 3.4e38f, 3.4e38f, 3.4e38f};
        int   besti[4] = {0x7fffffff, 0x7fffffff, 0x7fffffff, 0x7fffffff};
#pragma unroll
        for (int chunk = 0; chunk < 2; chunk++) {
            const int cbase = chunk * 128 + tc * 8;
            float acc[4][8];
#pragma unroll
            for (int i = 0; i < 4; i++)
#pragma unroll
                for (int j = 0; j < 8; j++) acc[i][j] = 0.f;

            // sequential fused-FMA over k ascending == BLAS sgemm microkernel order
#pragma unroll 8
            for (int k = 0; k < D; k++) {
                const float4 xv = *(const float4*)&xt[k][tt * 4];
                const float4 c0 = *(const float4*)&ct[k][cbase];
                const float4 c1 = *(const float4*)&ct[k][cbase + 4];
                const float xs[4] = {xv.x, xv.y, xv.z, xv.w};
                const float cs[8] = {c0.x, c0.y, c0.z, c0.w, c1.x, c1.y, c1.z, c1.w};
#pragma unroll
                for (int i = 0; i < 4; i++)
#pragma unroll
                    for (int j = 0; j < 8; j++)
                        acc[i][j] = __builtin_fmaf(xs[i], cs[j], acc[i][j]);
            }
            // d2 = fl(fl(x2 - 2*xc) + c2)  — matches np op order; 2*xc is exact
#pragma unroll
            for (int j = 0; j < 8; j++) {
                const float c2v = c2s[cbase + j];
#pragma unroll
                for (int i = 0; i < 4; i++) {
                    float t2 = x4[i] - 2.0f * acc[i][j];
                    float s  = t2 + c2v;
                    if (s < bestv[i]) { bestv[i] = s; besti[i] = cbase + j; }
                }
            }
        }
        // cross-lane argmin over the 16 code-threads (same tt); first-min tie-break
#pragma unroll
        for (int m = 1; m < 16; m <<= 1) {
#pragma unroll
            for (int i = 0; i < 4; i++) {
                float ov = __shfl_xor(bestv[i], m, 64);
                int   oi = __shfl_xor(besti[i], m, 64);
                if (ov < bestv[i] || (ov == bestv[i] && oi < besti[i])) {
                    bestv[i] = ov; besti[i] = oi;
                }
            }
        }
        if (tc == 0) {
#pragma unroll
            for (int i = 0; i < 4; i++) bidx[tt * 4 + i] = besti[i];
        }
        __syncthreads();

        // ---- rotation epilogue: 4 lanes per token, 8 dims each ----
        {
            const int tok = tid >> 2;
            const int sub = tid & 3;
            const size_t gtok = (size_t)tok0 + tok;
            const float4* xg = (const float4*)(x + gtok * D + sub * 8);
            float4 xa = xg[0], xb = xg[1];
            const int bi = bidx[tok];
            const float4* cg = (const float4*)(cb + (size_t)bi * D + sub * 8);
            float4 ca = cg[0], cbv = cg[1];

            float xs8[8] = {xa.x, xa.y, xa.z, xa.w, xb.x, xb.y, xb.z, xb.w};
            float cs8[8] = {ca.x, ca.y, ca.z, ca.w, cbv.x, cbv.y, cbv.z, cbv.w};

            float px2 = 0.f, pc2 = 0.f;
#pragma unroll
            for (int j = 0; j < 8; j++) { px2 = fmaf(xs8[j], xs8[j], px2); pc2 = fmaf(cs8[j], cs8[j], pc2); }
            float x2 = px2 + __shfl_xor(px2, 1, 64); x2 += __shfl_xor(x2, 2, 64);
            float c2 = pc2 + __shfl_xor(pc2, 1, 64); c2 += __shfl_xor(c2, 2, 64);
            const float inx = 1.f / fmaxf(sqrtf(x2), EPSF);
            const float inc = 1.f / fmaxf(sqrtf(c2), EPSF);

            float us8[8], qs8[8], ws8[8];
            float pw2 = 0.f;
#pragma unroll
            for (int j = 0; j < 8; j++) {
                us8[j] = xs8[j] * inx;
                qs8[j] = cs8[j] * inc;
                ws8[j] = us8[j] + qs8[j];
                pw2 = fmaf(ws8[j], ws8[j], pw2);
            }
            float w2 = pw2 + __shfl_xor(pw2, 1, 64); w2 += __shfl_xor(w2, 2, 64);
            const float inw = 1.f / fmaxf(sqrtf(w2), EPSF);

            float pew = 0.f, peu = 0.f;
#pragma unroll
            for (int j = 0; j < 8; j++) {
                ws8[j] *= inw;
                pew = fmaf(xs8[j], ws8[j], pew);
                peu = fmaf(xs8[j], us8[j], peu);
            }
            float ew = pew + __shfl_xor(pew, 1, 64); ew += __shfl_xor(ew, 2, 64);
            float eu = peu + __shfl_xor(peu, 1, 64); eu += __shfl_xor(eu, 2, 64);

            float ro[8];
#pragma unroll
            for (int j = 0; j < 8; j++)
                ro[j] = xs8[j] - 2.f * ew * ws8[j] + 2.f * eu * qs8[j];

            float4* og = (float4*)(out_rot + gtok * D + sub * 8);
            og[0] = make_float4(ro[0], ro[1], ro[2], ro[3]);
            og[1] = make_float4(ro[4], ro[5], ro[6], ro[7]);

            if (sub == 0) {
                out_idx[gtok] = (float)bi;
                atomicAdd(&hist[bi], 1.f);
            }
        }
        __syncthreads();   // protect xt/bidx/hist before next tile
    }

    // ---- flush per-block histogram ----
    if (use_ws) ws_hist[(size_t)blockIdx.x * KC + tid] = hist[tid];
    else        atomicAdd(&out_cnt[tid], hist[tid]);
}

// ---------------- tiny reduce: 768 block-partials -> 256 counts ----------------
__global__ __launch_bounds__(256) void vq_reduce(const float* __restrict__ ws,
                                                 float* __restrict__ out_cnt)
{
    const int c = blockIdx.x * 8 + (threadIdx.x >> 5);  // code
    const int l = threadIdx.x & 31;                     // lane within code-group
    float s = 0.f;
    for (int b = l; b < NBLK; b += 32) s += ws[(size_t)b * KC + c];
#pragma unroll
    for (int m = 1; m < 32; m <<= 1) s += __shfl_xor(s, m, 64);
    if (l == 0) out_cnt[c] = s;
}

extern "C" void kernel_launch(void* const* d_in, const int* in_sizes, int n_in,
                              void* d_out, int out_size, void* d_ws, size_t ws_size,
                              hipStream_t stream)
{
    const float* x  = (const float*)d_in[0];
    const float* cb = (const float*)d_in[1];
    float* out      = (float*)d_out;
    float* out_rot  = out;                                   // [524288*32]
    float* out_idx  = out + (size_t)N_TOK * D;               // [524288] (indices as float)
    float* out_cnt  = out_idx + N_TOK;                       // [256]

    const size_t ws_need = (size_t)NBLK * KC * sizeof(float);
    const int use_ws = (ws_size >= ws_need) ? 1 : 0;
    if (!use_ws) hipMemsetAsync(out_cnt, 0, KC * sizeof(float), stream);

    vq_main<<<NBLK, BLKT, 0, stream>>>(x, cb, out_rot, out_idx,
                                       (float*)d_ws, out_cnt, use_ws);
    if (use_ws) vq_reduce<<<32, 256, 0, stream>>>((const float*)d_ws, out_cnt);
}